// Round 1
// baseline (220.532 us; speedup 1.0000x reference)
//
#include <hip/hip_runtime.h>
#include <cmath>

#define NB 32
#define NS 256
#define NT 64
#define START_TAG 62
#define STOP_TAG 63
#define CL 8                 // matrices per chunk
#define NCH 32               // chunks per batch
#define GS 8.0f              // M = exp(f - GS)
#define LOG64 4.1588830833596715f

typedef __attribute__((ext_vector_type(8))) short short8;
typedef __attribute__((ext_vector_type(4))) float float4v;

union FragU { unsigned u[4]; short8 s; unsigned short h[8]; };

__device__ inline unsigned pkbf(float a, float b) {
  unsigned ua = (__float_as_uint(a) + 0x8000u) >> 16;
  unsigned ub = (__float_as_uint(b) + 0x8000u) & 0xffff0000u;
  return ua | ub;
}

// ---------------- Phase 1: wave-per-chunk matrix product, ZERO barriers -----
// R7 restructure: iterate the chunk's timesteps in REVERSE, so each new
// matrix enters the MFMA as the A operand in PLAIN (untransposed) layout,
// whose fragment loads are row-contiguous (float4), replacing the 64
// stride-256B scalar loads/lane of the old A^T pattern. Running product
// G = E_t1 * ... * E_tn lives in the B-frag (init = identity, in-register).
// Final store is contiguous 16B per fragment (cmat[j][c] = G[c][j] = P[j][c],
// same orientation combine_kernel always consumed).
__global__ __launch_bounds__(256) void chunk_kernel(
    const float* __restrict__ feat, const int* __restrict__ lengths,
    unsigned short* __restrict__ cmat, float* __restrict__ out) {
  if (blockIdx.x == 0 && threadIdx.x == 0) out[0] = 0.f;  // replaces memset launch

  const int wv  = threadIdx.x >> 6;
  const int gid = blockIdx.x * 4 + wv;        // 0..1023
  const int b   = gid >> 5;                   // NCH = 32
  const int c   = gid & 31;
  const int len = lengths[b];
  const int t1  = 1 + c * CL;
  const int nmat = min(len, t1 + CL) - t1;
  if (nmat <= 0) return;

  const int lane = threadIdx.x & 63;
  const int q  = lane >> 4;
  const int cc = lane & 15;

  const float* fb = feat + ((size_t)b * NS + t1) * (NT * NT);

  // Running product in B-frag layout: B[k'][n'] at (h,tj,lane(q,cc),j) is
  // element [32h+8q+j][16tj+cc]. Init to identity (no loads, exact).
  FragU BQ[2][4];
  #pragma unroll
  for (int h = 0; h < 2; ++h)
    #pragma unroll
    for (int tj = 0; tj < 4; ++tj) {
      BQ[h][tj].u[0] = 0u; BQ[h][tj].u[1] = 0u;
      BQ[h][tj].u[2] = 0u; BQ[h][tj].u[3] = 0u;
      const int d = 16 * tj + cc - 32 * h - 8 * q;
      if (0 <= d && d < 8) BQ[h][tj].h[d] = 0x3F80;   // bf16 1.0
    }

  // Prefetch LAST matrix of the chunk, plain-A pattern: row 16mi+cc,
  // cols 32kh+8q .. +7  →  two float4 loads per (mi,kh), fully coalesced.
  float4 rx[4][2], ry[4][2];
  {
    const float* p0 = fb + (size_t)(nmat - 1) * (NT * NT);
    #pragma unroll
    for (int mi = 0; mi < 4; ++mi)
      #pragma unroll
      for (int kh = 0; kh < 2; ++kh) {
        const float* p = p0 + (16 * mi + cc) * NT + 32 * kh + 8 * q;
        rx[mi][kh] = *(const float4*)p;
        ry[mi][kh] = *(const float4*)(p + 4);
      }
  }

  const int src0 = (((q & 1) * 2) << 4) | cc;
  const int src1 = src0 + 16;
  const bool hi = (q >> 1) != 0;

  float sh = GS;   // first (rightmost) matrix at shift GS, rest GS+LOG64
  for (int k = nmat - 1; k >= 0; --k) {
    // FA = exp(raw - sh): A-frag of plain E_{t1+k}
    FragU FA[4][2];
    #pragma unroll
    for (int mi = 0; mi < 4; ++mi)
      #pragma unroll
      for (int kh = 0; kh < 2; ++kh) {
        const float4 x = rx[mi][kh], y = ry[mi][kh];
        FA[mi][kh].u[0] = pkbf(__expf(x.x - sh), __expf(x.y - sh));
        FA[mi][kh].u[1] = pkbf(__expf(x.z - sh), __expf(x.w - sh));
        FA[mi][kh].u[2] = pkbf(__expf(y.x - sh), __expf(y.y - sh));
        FA[mi][kh].u[3] = pkbf(__expf(y.z - sh), __expf(y.w - sh));
      }
    sh = GS + LOG64;

    // prefetch next (previous-timestep) matrix, same contiguous pattern
    if (k > 0) {
      const float* p0 = fb + (size_t)(k - 1) * (NT * NT);
      #pragma unroll
      for (int mi = 0; mi < 4; ++mi)
        #pragma unroll
        for (int kh = 0; kh < 2; ++kh) {
          const float* p = p0 + (16 * mi + cc) * NT + 32 * kh + 8 * q;
          rx[mi][kh] = *(const float4*)p;
          ry[mi][kh] = *(const float4*)(p + 4);
        }
    }

    // D = E_{t1+k} * R   (prepend; reverse iteration => final R = E_t1*...*E_tn)
    float4v acc[4][4];
    #pragma unroll
    for (int ti = 0; ti < 4; ++ti)
      #pragma unroll
      for (int tj = 0; tj < 4; ++tj) {
        float4v z = {0.f, 0.f, 0.f, 0.f};
        z = __builtin_amdgcn_mfma_f32_16x16x32_bf16(FA[ti][0].s, BQ[0][tj].s, z, 0, 0, 0);
        acc[ti][tj] = __builtin_amdgcn_mfma_f32_16x16x32_bf16(FA[ti][1].s, BQ[1][tj].s, z, 0, 0, 0);
      }

    // repack acc (C-layout) -> B-frag (identical layout transform as before)
    unsigned pk01[4][4], pk23[4][4];
    #pragma unroll
    for (int ti = 0; ti < 4; ++ti)
      #pragma unroll
      for (int tj = 0; tj < 4; ++tj) {
        pk01[ti][tj] = pkbf(acc[ti][tj][0], acc[ti][tj][1]);
        pk23[ti][tj] = pkbf(acc[ti][tj][2], acc[ti][tj][3]);
      }

    #pragma unroll
    for (int h = 0; h < 2; ++h)
      #pragma unroll
      for (int tj = 0; tj < 4; ++tj) {
        unsigned a0 = (unsigned)__shfl((int)pk01[2 * h][tj],     src0);
        unsigned b0 = (unsigned)__shfl((int)pk01[2 * h + 1][tj], src0);
        unsigned a1 = (unsigned)__shfl((int)pk23[2 * h][tj],     src0);
        unsigned b1 = (unsigned)__shfl((int)pk23[2 * h + 1][tj], src0);
        unsigned a2 = (unsigned)__shfl((int)pk01[2 * h][tj],     src1);
        unsigned b2 = (unsigned)__shfl((int)pk01[2 * h + 1][tj], src1);
        unsigned a3 = (unsigned)__shfl((int)pk23[2 * h][tj],     src1);
        unsigned b3 = (unsigned)__shfl((int)pk23[2 * h + 1][tj], src1);
        BQ[h][tj].u[0] = hi ? b0 : a0;
        BQ[h][tj].u[1] = hi ? b1 : a1;
        BQ[h][tj].u[2] = hi ? b2 : a2;
        BQ[h][tj].u[3] = hi ? b3 : a3;
      }
  }

  // Store transposed: cmat[j][c] = G[c][j]  (= P[j][c], what combine reads).
  // B-frag element (h,tj,j) = G[32h+8q+j][16tj+cc] → dst[(16tj+cc)*64 + 32h+8q+j]:
  // contiguous in j → one 16B store per fragment, 16B-aligned.
  unsigned short* dst = cmat + ((size_t)b * NCH + c) * (NT * NT);
  #pragma unroll
  for (int h = 0; h < 2; ++h)
    #pragma unroll
    for (int tj = 0; tj < 4; ++tj)
      *(short8*)(dst + (16 * tj + cc) * NT + 32 * h + 8 * q) = BQ[h][tj].s;
}

// ---------------- Phase 2: sequential combine + gold + finalize -------------
// R6-proven combine body (depth-3 prefetch ring), standalone launch. Unchanged.
__global__ __launch_bounds__(64) void combine_kernel(
    const float* __restrict__ feat, const int* __restrict__ targets,
    const int* __restrict__ lengths, const unsigned int* __restrict__ cmat,
    float* __restrict__ out) {
  const int b = blockIdx.x;
  const int j = threadIdx.x;
  __shared__ float sv[NT];
  const int len = lengths[b];
  const float* f0 = feat + (size_t)b * NS * (NT * NT);

  float gold = 0.f;
  #pragma unroll
  for (int g = 0; g < 4; ++g) {
    const int s = j + 64 * g;
    if (s < len) {
      const int tgt = targets[b * NS + s];
      gold += f0[(size_t)s * (NT * NT) + tgt];
    }
  }

  float x = f0[START_TAG * NT + j];
  float m = x;
  #pragma unroll
  for (int off = 32; off; off >>= 1) m = fmaxf(m, __shfl_xor(m, off));
  float v = __expf(x - m);
  float L = m;

  const int nch = (len - 1 + CL - 1) / CL;
  const uint4* base = (const uint4*)cmat + (size_t)b * NCH * 512 + j * 8;

  uint4 QA[8], QB[8], QC[8];
  auto LQ = [&](uint4* D, int c2) {
    if (c2 < nch) {
      const uint4* P = base + (size_t)c2 * 512;
      #pragma unroll
      for (int w = 0; w < 8; ++w) D[w] = P[w];
    }
  };
  auto STEP = [&](const uint4* Q, int c2) {
    sv[j] = v;
    __builtin_amdgcn_wave_barrier();
    float ac0 = 0.f, ac1 = 0.f, ac2 = 0.f, ac3 = 0.f;
    const float4* svp = (const float4*)sv;
    #pragma unroll
    for (int w = 0; w < 8; ++w) {
      uint4 qq = Q[w];
      float4 s0 = svp[2 * w], s1 = svp[2 * w + 1];
      ac0 = fmaf(__uint_as_float(qq.x << 16), s0.x, ac0);
      ac1 = fmaf(__uint_as_float(qq.x & 0xffff0000u), s0.y, ac1);
      ac2 = fmaf(__uint_as_float(qq.y << 16), s0.z, ac2);
      ac3 = fmaf(__uint_as_float(qq.y & 0xffff0000u), s0.w, ac3);
      ac0 = fmaf(__uint_as_float(qq.z << 16), s1.x, ac0);
      ac1 = fmaf(__uint_as_float(qq.z & 0xffff0000u), s1.y, ac1);
      ac2 = fmaf(__uint_as_float(qq.w << 16), s1.z, ac2);
      ac3 = fmaf(__uint_as_float(qq.w & 0xffff0000u), s1.w, ac3);
    }
    float acc = (ac0 + ac1) + (ac2 + ac3);
    __builtin_amdgcn_wave_barrier();
    const int tt1 = 1 + c2 * CL;
    const int nm = min(len, tt1 + CL) - tt1;
    L += (float)nm * GS + (float)(nm - 1) * LOG64;
    float mm = acc;
    #pragma unroll
    for (int off = 32; off; off >>= 1) mm = fmaxf(mm, __shfl_xor(mm, off));
    v = acc / mm;
    L += __logf(mm);
  };

  LQ(QA, 0); LQ(QB, 1); LQ(QC, 2);
  for (int c2 = 0; c2 < nch; c2 += 3) {
    STEP(QA, c2);
    LQ(QA, c2 + 3);
    if (c2 + 1 < nch) { STEP(QB, c2 + 1); LQ(QB, c2 + 4); }
    if (c2 + 2 < nch) { STEP(QC, c2 + 2); LQ(QC, c2 + 5); }
  }

  float lv = __logf(v);
  float path = L + __shfl(lv, STOP_TAG);

  #pragma unroll
  for (int off = 32; off; off >>= 1) gold += __shfl_down(gold, off);
  if (j == 0) atomicAdd(out, (path - gold) * (1.0f / (float)NB));
}

extern "C" void kernel_launch(void* const* d_in, const int* in_sizes, int n_in,
                              void* d_out, int out_size, void* d_ws, size_t ws_size,
                              hipStream_t stream) {
  const float* feat    = (const float*)d_in[0];
  const int*   targets = (const int*)d_in[1];
  const int*   lengths = (const int*)d_in[2];
  unsigned short* cmat = (unsigned short*)d_ws;   // 8 MB bf16 chunk products
  float* out = (float*)d_out;

  chunk_kernel<<<NB * NCH / 4, 256, 0, stream>>>(feat, lengths, cmat, out);
  combine_kernel<<<NB, 64, 0, stream>>>(feat, targets, lengths,
                                        (const unsigned int*)cmat, out);
}